// Round 2
// baseline (44.687 us; speedup 1.0000x reference)
//
#include <hip/hip_runtime.h>

#define NQ 14
#define DIM (1 << NQ)       // 16384
#define NT 512

typedef float2 c32;

__device__ __forceinline__ c32 cmul(c32 a, c32 b) {
  return make_float2(a.x * b.x - a.y * b.y, a.x * b.y + a.y * b.x);
}

// RY on local bit K of a 32-element register subcube (compile-time indices only)
template<int K>
__device__ __forceinline__ void apply_ry(c32* v, float c, float s) {
#pragma unroll
  for (int m = 0; m < 16; ++m) {
    const int j0 = ((m >> K) << (K + 1)) | (m & ((1 << K) - 1));
    const int j1 = j0 | (1 << K);
    const c32 a0 = v[j0], a1 = v[j1];
    v[j0] = make_float2(c * a0.x - s * a1.x, c * a0.y - s * a1.y);
    v[j1] = make_float2(s * a0.x + c * a1.x, s * a0.y + c * a1.y);
  }
}

// <X> partial over local bit K: sum Re(conj(a0)*a1)
template<int K>
__device__ __forceinline__ float expv(const c32* v) {
  float acc = 0.f;
#pragma unroll
  for (int m = 0; m < 16; ++m) {
    const int j0 = ((m >> K) << (K + 1)) | (m & ((1 << K) - 1));
    const int j1 = j0 | (1 << K);
    acc += v[j0].x * v[j1].x + v[j0].y * v[j1].y;
  }
  return acc;
}

// ---- DPP lane exchange: 0xB1 = quad_perm [1,0,3,2] (xor lane-bit0), 0x4E = [2,3,0,1] (xor lane-bit1)
template<int CTRL>
__device__ __forceinline__ float dppf(float x) {
  return __int_as_float(__builtin_amdgcn_mov_dpp(__float_as_int(x), CTRL, 0xF, 0xF, true));
}

// RY on a lane bit: new = c*own + se*partner, se = +s if lane-bit set else -s
template<int CTRL>
__device__ __forceinline__ void dpp_ry(c32* v, float c, float se) {
#pragma unroll
  for (int j = 0; j < 32; ++j) {
    const float px = dppf<CTRL>(v[j].x), py = dppf<CTRL>(v[j].y);
    v[j] = make_float2(c * v[j].x + se * px, c * v[j].y + se * py);
  }
}

// <X> over a lane bit; summed over all lanes this yields 2*S (each pair counted twice)
template<int CTRL>
__device__ __forceinline__ float dpp_expv(const c32* v) {
  float acc = 0.f;
#pragma unroll
  for (int j = 0; j < 32; ++j)
    acc += v[j].x * dppf<CTRL>(v[j].x) + v[j].y * dppf<CTRL>(v[j].y);
  return acc;
}

__device__ __forceinline__ void wave_reduce_atomic(float val, float* dst) {
#pragma unroll
  for (int off = 32; off; off >>= 1) val += __shfl_down(val, off);
  if ((threadIdx.x & 63) == 0) atomicAdd(dst, val);
}

// per-wire 2-vector u = RY(q0) * RX(n) * RY(n) |0>
__device__ __forceinline__ void wire_u(float nz, float q0, c32& u0, c32& u1) {
  float sn, cn, sy, cy;
  __sincosf(0.5f * nz, &sn, &cn);
  __sincosf(0.5f * q0, &sy, &cy);
  const float cc = cn * cn, ss = sn * sn, cs = cn * sn;
  u0 = make_float2(cy * cc - sy * cs, sy * cs - cy * ss);
  u1 = make_float2(sy * cc + cy * cs, -sy * ss - cy * cs);
}

// ---- gate groups. Layout A: amp i = (t<<5)|j; local bits 0-4 = wires 13..9; lane bits -> wires 8,7.
__device__ __forceinline__ void gatesA(c32* v, const float* __restrict__ qp, int l, int t) {
  float c[5], s[5];
#pragma unroll
  for (int k = 0; k < 5; ++k) __sincosf(0.5f * qp[l * NQ + (13 - k)], &s[k], &c[k]);
  apply_ry<0>(v, c[0], s[0]);
  apply_ry<1>(v, c[1], s[1]);
  apply_ry<2>(v, c[2], s[2]);
  apply_ry<3>(v, c[3], s[3]);
  apply_ry<4>(v, c[4], s[4]);
  float c8, s8, c7, s7;
  __sincosf(0.5f * qp[l * NQ + 8], &s8, &c8);
  __sincosf(0.5f * qp[l * NQ + 7], &s7, &c7);
  dpp_ry<0xB1>(v, c8, (t & 1) ? s8 : -s8);   // wire 8 = global bit 5 = lane bit 0
  dpp_ry<0x4E>(v, c7, (t & 2) ? s7 : -s7);   // wire 7 = global bit 6 = lane bit 1
}

// Layout B: amp i = (j<<9) | ((t&3)<<7) | (t>>2); local bits -> wires 4..0; lane bits -> wires 6,5.
__device__ __forceinline__ void gatesB(c32* v, const float* __restrict__ qp, int l, int t) {
  float c[5], s[5];
#pragma unroll
  for (int k = 0; k < 5; ++k) __sincosf(0.5f * qp[l * NQ + (4 - k)], &s[k], &c[k]);
  apply_ry<0>(v, c[0], s[0]);
  apply_ry<1>(v, c[1], s[1]);
  apply_ry<2>(v, c[2], s[2]);
  apply_ry<3>(v, c[3], s[3]);
  apply_ry<4>(v, c[4], s[4]);
  float c6, s6, c5, s5;
  __sincosf(0.5f * qp[l * NQ + 6], &s6, &c6);
  __sincosf(0.5f * qp[l * NQ + 5], &s5, &c5);
  dpp_ry<0xB1>(v, c6, (t & 1) ? s6 : -s6);   // wire 6 = global bit 7 = lane bit 0
  dpp_ry<0x4E>(v, c5, (t & 2) ? s5 : -s5);   // wire 5 = global bit 8 = lane bit 1
}

// ---- CZ ladder sign: parity(i & (i>>1))
__device__ __forceinline__ void czA(c32* v, int t) {   // i = (t<<5)|j
  const int pa = __popc(t & (t >> 1)) & 1;
  const int t0 = t & 1;
#pragma unroll
  for (int j = 0; j < 32; ++j) {
    const int sgn = pa ^ (__popc(j & (j >> 1)) & 1) ^ (((j >> 4) & 1) & t0);
    if (sgn) { v[j].x = -v[j].x; v[j].y = -v[j].y; }
  }
}
__device__ __forceinline__ void czB(c32* v, int t) {   // i = (j<<9)|((t&3)<<7)|(t>>2)
  const int lo = t >> 2, m = t & 3;
  const int pt = (__popc(lo & (lo >> 1)) & 1) ^ (((lo >> 6) & 1) & (m & 1)) ^ ((m & 1) & ((m >> 1) & 1));
  const int m1 = (m >> 1) & 1;
#pragma unroll
  for (int j = 0; j < 32; ++j) {
    const int sgn = pt ^ (__popc(j & (j >> 1)) & 1) ^ (m1 & (j & 1));
    if (sgn) { v[j].x = -v[j].x; v[j].y = -v[j].y; }
  }
}

// ---- swizzled addressing: phys = i ^ ((i>>5)&31); conflict-free in both layouts
__device__ __forceinline__ int addrA(int t, int j) { return (t << 5) | (j ^ (t & 31)); }
__device__ __forceinline__ int baseB_of(int t) {
  return ((t & 3) << 7) | ((t >> 2) ^ ((t >> 7) & 3) ^ ((t & 3) << 2));
}
__device__ __forceinline__ int addrB(int bB, int j) { return (j << 9) | (bB ^ ((j & 1) << 4)); }

__global__ __launch_bounds__(NT, 2) void qsim_kernel(
    const float* __restrict__ noise, const float* __restrict__ qp,
    float* __restrict__ out) {
  __shared__ c32 st[DIM];       // 128 KiB, swizzled layout
  __shared__ float exps[NQ];
  const int b = blockIdx.x;
  const int t = threadIdx.x;
  if (t < NQ) exps[t] = 0.f;

  // ---- product state: (RX*RY)(noise) + layer-0 RY on all 14 wires, pure registers ----
  c32 v[32];
  {
    c32 h = make_float2(1.f, 0.f);          // product over thread bits (global bits 5..13)
#pragma unroll
    for (int p = 5; p < 14; ++p) {
      c32 u0, u1;
      wire_u(noise[b * NQ + (13 - p)], qp[13 - p], u0, u1);
      const c32 pick = ((t >> (p - 5)) & 1) ? u1 : u0;
      h = cmul(h, pick);
    }
    {
      c32 u0, u1;
      wire_u(noise[b * NQ + 13], qp[13], u0, u1);
      v[0] = u0; v[1] = u1;
    }
#define BSTEP(P)                                                           \
    {                                                                      \
      c32 u0, u1;                                                          \
      wire_u(noise[b * NQ + (13 - (P))], qp[13 - (P)], u0, u1);            \
      _Pragma("unroll")                                                    \
      for (int j = 0; j < (1 << (P)); ++j) {                               \
        v[j | (1 << (P))] = cmul(v[j], u1);                                \
        v[j] = cmul(v[j], u0);                                             \
      }                                                                    \
    }
    BSTEP(1) BSTEP(2) BSTEP(3) BSTEP(4)
#undef BSTEP
#pragma unroll
    for (int j = 0; j < 32; ++j) v[j] = cmul(v[j], h);
  }
  czA(v, t);           // CZ of layer 0
  gatesA(v, qp, 1, t); // layer-1 gates on wires 7-13, in registers
#pragma unroll
  for (int j = 0; j < 32; ++j) st[addrA(t, j)] = v[j];
  __syncthreads();

  const int bB = baseB_of(t);

  // ---- alternating single-pass-per-layer schedule ----
  // P1 [layout B]: B(1) + CZ(1) + B(2)
#pragma unroll
  for (int j = 0; j < 32; ++j) v[j] = st[addrB(bB, j)];
  gatesB(v, qp, 1, t); czB(v, t); gatesB(v, qp, 2, t);
#pragma unroll
  for (int j = 0; j < 32; ++j) st[addrB(bB, j)] = v[j];
  __syncthreads();

  // P2 [layout A]: A(2) + CZ(2) + A(3)
#pragma unroll
  for (int j = 0; j < 32; ++j) v[j] = st[addrA(t, j)];
  gatesA(v, qp, 2, t); czA(v, t); gatesA(v, qp, 3, t);
#pragma unroll
  for (int j = 0; j < 32; ++j) st[addrA(t, j)] = v[j];
  __syncthreads();

  // P3 [layout B]: B(3) + CZ(3) + B(4)
#pragma unroll
  for (int j = 0; j < 32; ++j) v[j] = st[addrB(bB, j)];
  gatesB(v, qp, 3, t); czB(v, t); gatesB(v, qp, 4, t);
#pragma unroll
  for (int j = 0; j < 32; ++j) st[addrB(bB, j)] = v[j];
  __syncthreads();

  // P4 [layout A]: A(4) + CZ(4) + A(5)
#pragma unroll
  for (int j = 0; j < 32; ++j) v[j] = st[addrA(t, j)];
  gatesA(v, qp, 4, t); czA(v, t); gatesA(v, qp, 5, t);
#pragma unroll
  for (int j = 0; j < 32; ++j) st[addrA(t, j)] = v[j];
  __syncthreads();

  // P5 [layout B]: B(5) + CZ(5) + <X> for wires 0-6, write final state
#pragma unroll
  for (int j = 0; j < 32; ++j) v[j] = st[addrB(bB, j)];
  gatesB(v, qp, 5, t); czB(v, t);
  wave_reduce_atomic(expv<0>(v), &exps[4]);
  wave_reduce_atomic(expv<1>(v), &exps[3]);
  wave_reduce_atomic(expv<2>(v), &exps[2]);
  wave_reduce_atomic(expv<3>(v), &exps[1]);
  wave_reduce_atomic(expv<4>(v), &exps[0]);
  wave_reduce_atomic(dpp_expv<0xB1>(v), &exps[6]);
  wave_reduce_atomic(dpp_expv<0x4E>(v), &exps[5]);
#pragma unroll
  for (int j = 0; j < 32; ++j) st[addrB(bB, j)] = v[j];
  __syncthreads();

  // P6 [layout A, read-only]: <X> for wires 7-13
#pragma unroll
  for (int j = 0; j < 32; ++j) v[j] = st[addrA(t, j)];
  wave_reduce_atomic(expv<0>(v), &exps[13]);
  wave_reduce_atomic(expv<1>(v), &exps[12]);
  wave_reduce_atomic(expv<2>(v), &exps[11]);
  wave_reduce_atomic(expv<3>(v), &exps[10]);
  wave_reduce_atomic(expv<4>(v), &exps[9]);
  wave_reduce_atomic(dpp_expv<0xB1>(v), &exps[8]);
  wave_reduce_atomic(dpp_expv<0x4E>(v), &exps[7]);
  __syncthreads();

  if (t < NQ) {
    // register-pair wires hold S (need x2); DPP wires hold 2S already (pairs double-counted)
    const float f = (t >= 5 && t <= 8) ? 1.f : 2.f;
    out[b * NQ + t] = f * exps[t];
  }
}

extern "C" void kernel_launch(void* const* d_in, const int* in_sizes, int n_in,
                              void* d_out, int out_size, void* d_ws, size_t ws_size,
                              hipStream_t stream) {
  const float* noise = (const float*)d_in[0];  // [64, 14]
  const float* qp    = (const float*)d_in[1];  // [6, 14]
  float* out = (float*)d_out;                  // [64, 14]
  qsim_kernel<<<64, NT, 0, stream>>>(noise, qp, out);
}

// Round 3
// 41.683 us; speedup vs baseline: 1.0721x; 1.0721x over previous
//
#include <hip/hip_runtime.h>

#define NQ 14
#define DIM (1 << NQ)       // 16384
#define NT 512

typedef float __attribute__((ext_vector_type(2))) f2;   // packed (re,im) or (x,y)

__device__ __forceinline__ f2 pkfma(f2 a, f2 b, f2 c) {
  return __builtin_elementwise_fma(a, b, c);            // -> v_pk_fma_f32
}
__device__ __forceinline__ f2 sp(float x) { f2 r; r.x = x; r.y = x; return r; }

__device__ __forceinline__ f2 cmul(f2 a, f2 b) {
  f2 r; r.x = a.x * b.x - a.y * b.y; r.y = a.x * b.y + a.y * b.x; return r;
}

// RY on local bit K of a 32-element register subcube (compile-time indices only)
template<int K>
__device__ __forceinline__ void apply_ry(f2* v, float c, float s) {
  const f2 vc = sp(c), vs = sp(s), vsn = sp(-s);
#pragma unroll
  for (int m = 0; m < 16; ++m) {
    const int j0 = ((m >> K) << (K + 1)) | (m & ((1 << K) - 1));
    const int j1 = j0 | (1 << K);
    const f2 a0 = v[j0], a1 = v[j1];
    v[j0] = pkfma(a1, vsn, a0 * vc);    // c*a0 - s*a1  (both components)
    v[j1] = pkfma(a0, vs,  a1 * vc);    // s*a0 + c*a1
  }
}

// <X> partial over local bit K: sum Re(conj(a0)*a1) = x0x1 + y0y1, packed accum
template<int K>
__device__ __forceinline__ float expv(const f2* v) {
  f2 acc = sp(0.f);
#pragma unroll
  for (int m = 0; m < 16; ++m) {
    const int j0 = ((m >> K) << (K + 1)) | (m & ((1 << K) - 1));
    const int j1 = j0 | (1 << K);
    acc = pkfma(v[j0], v[j1], acc);
  }
  return acc.x + acc.y;
}

// ---- DPP lane exchange: 0xB1 = quad_perm [1,0,3,2] (xor bit0), 0x4E = [2,3,0,1] (xor bit1)
template<int CTRL>
__device__ __forceinline__ float dppf(float x) {
  return __int_as_float(__builtin_amdgcn_mov_dpp(__float_as_int(x), CTRL, 0xF, 0xF, true));
}

template<int CTRL>
__device__ __forceinline__ void dpp_ry(f2* v, float c, float se) {
  const f2 vc = sp(c), vse = sp(se);
#pragma unroll
  for (int j = 0; j < 32; ++j) {
    f2 p; p.x = dppf<CTRL>(v[j].x); p.y = dppf<CTRL>(v[j].y);
    v[j] = pkfma(p, vse, v[j] * vc);
  }
}

template<int CTRL>
__device__ __forceinline__ float dpp_expv(const f2* v) {
  f2 acc = sp(0.f);
#pragma unroll
  for (int j = 0; j < 32; ++j) {
    f2 p; p.x = dppf<CTRL>(v[j].x); p.y = dppf<CTRL>(v[j].y);
    acc = pkfma(v[j], p, acc);
  }
  return acc.x + acc.y;
}

__device__ __forceinline__ void wave_reduce_atomic(float val, float* dst) {
#pragma unroll
  for (int off = 32; off; off >>= 1) val += __shfl_down(val, off);
  if ((threadIdx.x & 63) == 0) atomicAdd(dst, val);
}

// per-wire 2-vector u = RY(q0) * RX(n) * RY(n) |0>
__device__ __forceinline__ void wire_u(float nz, float q0, f2& u0, f2& u1) {
  float sn, cn, sy, cy;
  __sincosf(0.5f * nz, &sn, &cn);
  __sincosf(0.5f * q0, &sy, &cy);
  const float cc = cn * cn, ss = sn * sn, cs = cn * sn;
  u0.x = cy * cc - sy * cs;  u0.y = sy * cs - cy * ss;
  u1.x = sy * cc + cy * cs;  u1.y = -sy * ss - cy * cs;
}

// ---- CZ ladder sign: parity(i & (i>>1)), applied as a single packed mul per amp
__device__ __forceinline__ void czA(f2* v, int t) {   // i = (t<<5)|j
  const int pa = __popc(t & (t >> 1)) & 1, t0 = t & 1;
  const float f0 = pa ? -1.f : 1.f;
  const float f1 = (pa ^ t0) ? -1.f : 1.f;
#pragma unroll
  for (int j = 0; j < 32; ++j) {
    const bool ct = __popc(j & (j >> 1)) & 1;    // compile-time
    const float f = (j & 16) ? f1 : f0;
    v[j] = v[j] * sp(ct ? -f : f);
  }
}
__device__ __forceinline__ void czB(f2* v, int t) {   // i = (j<<9)|((t&3)<<7)|(t>>2)
  const int lo = t >> 2, m = t & 3;
  const int pt = (__popc(lo & (lo >> 1)) & 1) ^ (((lo >> 6) & 1) & (m & 1)) ^ ((m & 1) & ((m >> 1) & 1));
  const int m1 = (m >> 1) & 1;
  const float f0 = pt ? -1.f : 1.f;
  const float f1 = (pt ^ m1) ? -1.f : 1.f;
#pragma unroll
  for (int j = 0; j < 32; ++j) {
    const bool ct = __popc(j & (j >> 1)) & 1;    // compile-time
    const float f = (j & 1) ? f1 : f0;
    v[j] = v[j] * sp(ct ? -f : f);
  }
}

// ---- swizzled addressing: phys = i ^ ((i>>5)&31); conflict-free in both layouts
__device__ __forceinline__ int addrA(int t, int j) { return (t << 5) | (j ^ (t & 31)); }
__device__ __forceinline__ int baseB_of(int t) {
  return ((t & 3) << 7) | ((t >> 2) ^ ((t >> 7) & 3) ^ ((t & 3) << 2));
}
__device__ __forceinline__ int addrB(int bB, int j) { return (j << 9) | (bB ^ ((j & 1) << 4)); }

__global__ __launch_bounds__(NT, 2) void qsim_kernel(
    const float* __restrict__ noise, const float* __restrict__ qp,
    float* __restrict__ out) {
  __shared__ f2 st[DIM];            // 128 KiB, swizzled layout
  __shared__ f2 csTab[5 * NQ];      // layers 1..5: (cos, sin) per wire
  __shared__ f2 uTab[NQ][2];        // encoding+layer0 per-wire 2-vectors
  __shared__ float exps[NQ];
  const int b = blockIdx.x;
  const int t = threadIdx.x;

  // ---- one-time per-block tables: all transcendentals happen here ----
  if (t < 5 * NQ) {
    float s, c; __sincosf(0.5f * qp[NQ + t], &s, &c);
    f2 r; r.x = c; r.y = s; csTab[t] = r;
  }
  if (t < NQ) {
    exps[t] = 0.f;
    f2 u0, u1; wire_u(noise[b * NQ + t], qp[t], u0, u1);
    uTab[t][0] = u0; uTab[t][1] = u1;
  }
  __syncthreads();

  // ---- gate groups (read broadcast (c,s) from csTab) ----
  // Layout A: amp i=(t<<5)|j; reg bits 0-4 = wires 13..9; lane bits 0,1 = wires 8,7.
  // Layout B: amp i=(j<<9)|((t&3)<<7)|(t>>2); reg bits = wires 4..0; lane bits 0,1 = wires 6,5.
#define GATES_A(l)                                                          \
  {                                                                         \
    _Pragma("unroll")                                                       \
    for (int k = 0; k < 5; ++k) {                                           \
      const f2 cs = csTab[((l) - 1) * NQ + (13 - k)];                       \
      switch (k) {                                                          \
        case 0: apply_ry<0>(v, cs.x, cs.y); break;                          \
        case 1: apply_ry<1>(v, cs.x, cs.y); break;                          \
        case 2: apply_ry<2>(v, cs.x, cs.y); break;                          \
        case 3: apply_ry<3>(v, cs.x, cs.y); break;                          \
        case 4: apply_ry<4>(v, cs.x, cs.y); break;                          \
      }                                                                     \
    }                                                                       \
    const f2 c8 = csTab[((l) - 1) * NQ + 8], c7 = csTab[((l) - 1) * NQ + 7];\
    dpp_ry<0xB1>(v, c8.x, (t & 1) ? c8.y : -c8.y);                          \
    dpp_ry<0x4E>(v, c7.x, (t & 2) ? c7.y : -c7.y);                          \
  }
#define GATES_B(l)                                                          \
  {                                                                         \
    _Pragma("unroll")                                                       \
    for (int k = 0; k < 5; ++k) {                                           \
      const f2 cs = csTab[((l) - 1) * NQ + (4 - k)];                        \
      switch (k) {                                                          \
        case 0: apply_ry<0>(v, cs.x, cs.y); break;                          \
        case 1: apply_ry<1>(v, cs.x, cs.y); break;                          \
        case 2: apply_ry<2>(v, cs.x, cs.y); break;                          \
        case 3: apply_ry<3>(v, cs.x, cs.y); break;                          \
        case 4: apply_ry<4>(v, cs.x, cs.y); break;                          \
      }                                                                     \
    }                                                                       \
    const f2 c6 = csTab[((l) - 1) * NQ + 6], c5 = csTab[((l) - 1) * NQ + 5];\
    dpp_ry<0xB1>(v, c6.x, (t & 1) ? c6.y : -c6.y);                          \
    dpp_ry<0x4E>(v, c5.x, (t & 2) ? c5.y : -c5.y);                          \
  }

  // ---- product state: encoding + layer-0 RY on all 14 wires, pure registers ----
  f2 v[32];
  {
    f2 h; h.x = 1.f; h.y = 0.f;        // product over thread bits (global bits 5..13)
#pragma unroll
    for (int p = 5; p < 14; ++p)
      h = cmul(h, uTab[13 - p][(t >> (p - 5)) & 1]);
    v[0] = uTab[13][0]; v[1] = uTab[13][1];
#define BSTEP(P)                                                            \
    {                                                                       \
      const f2 u0 = uTab[13 - (P)][0], u1 = uTab[13 - (P)][1];              \
      _Pragma("unroll")                                                     \
      for (int j = 0; j < (1 << (P)); ++j) {                                \
        v[j | (1 << (P))] = cmul(v[j], u1);                                 \
        v[j] = cmul(v[j], u0);                                              \
      }                                                                     \
    }
    BSTEP(1) BSTEP(2) BSTEP(3) BSTEP(4)
#undef BSTEP
#pragma unroll
    for (int j = 0; j < 32; ++j) v[j] = cmul(v[j], h);
  }
  czA(v, t);        // CZ of layer 0
  GATES_A(1)        // layer-1 gates on wires 7-13, in registers
#pragma unroll
  for (int j = 0; j < 32; ++j) st[addrA(t, j)] = v[j];
  __syncthreads();

  const int bB = baseB_of(t);

  // P1 [layout B]: B(1) + CZ(1) + B(2)
#pragma unroll
  for (int j = 0; j < 32; ++j) v[j] = st[addrB(bB, j)];
  GATES_B(1) czB(v, t); GATES_B(2)
#pragma unroll
  for (int j = 0; j < 32; ++j) st[addrB(bB, j)] = v[j];
  __syncthreads();

  // P2 [layout A]: A(2) + CZ(2) + A(3)
#pragma unroll
  for (int j = 0; j < 32; ++j) v[j] = st[addrA(t, j)];
  GATES_A(2) czA(v, t); GATES_A(3)
#pragma unroll
  for (int j = 0; j < 32; ++j) st[addrA(t, j)] = v[j];
  __syncthreads();

  // P3 [layout B]: B(3) + CZ(3) + B(4)
#pragma unroll
  for (int j = 0; j < 32; ++j) v[j] = st[addrB(bB, j)];
  GATES_B(3) czB(v, t); GATES_B(4)
#pragma unroll
  for (int j = 0; j < 32; ++j) st[addrB(bB, j)] = v[j];
  __syncthreads();

  // P4 [layout A]: A(4) + CZ(4) + A(5)
#pragma unroll
  for (int j = 0; j < 32; ++j) v[j] = st[addrA(t, j)];
  GATES_A(4) czA(v, t); GATES_A(5)
#pragma unroll
  for (int j = 0; j < 32; ++j) st[addrA(t, j)] = v[j];
  __syncthreads();

  // P5 [layout B]: B(5) + CZ(5) + <X> for wires 0-6, write final state
#pragma unroll
  for (int j = 0; j < 32; ++j) v[j] = st[addrB(bB, j)];
  GATES_B(5) czB(v, t);
  wave_reduce_atomic(expv<0>(v), &exps[4]);
  wave_reduce_atomic(expv<1>(v), &exps[3]);
  wave_reduce_atomic(expv<2>(v), &exps[2]);
  wave_reduce_atomic(expv<3>(v), &exps[1]);
  wave_reduce_atomic(expv<4>(v), &exps[0]);
  wave_reduce_atomic(dpp_expv<0xB1>(v), &exps[6]);
  wave_reduce_atomic(dpp_expv<0x4E>(v), &exps[5]);
#pragma unroll
  for (int j = 0; j < 32; ++j) st[addrB(bB, j)] = v[j];
  __syncthreads();

  // P6 [layout A, read-only]: <X> for wires 7-13
#pragma unroll
  for (int j = 0; j < 32; ++j) v[j] = st[addrA(t, j)];
  wave_reduce_atomic(expv<0>(v), &exps[13]);
  wave_reduce_atomic(expv<1>(v), &exps[12]);
  wave_reduce_atomic(expv<2>(v), &exps[11]);
  wave_reduce_atomic(expv<3>(v), &exps[10]);
  wave_reduce_atomic(expv<4>(v), &exps[9]);
  wave_reduce_atomic(dpp_expv<0xB1>(v), &exps[8]);
  wave_reduce_atomic(dpp_expv<0x4E>(v), &exps[7]);
  __syncthreads();

  if (t < NQ) {
    // register-pair wires hold S (need x2); DPP wires hold 2S already (pairs double-counted)
    const float f = (t >= 5 && t <= 8) ? 1.f : 2.f;
    out[b * NQ + t] = f * exps[t];
  }
#undef GATES_A
#undef GATES_B
}

extern "C" void kernel_launch(void* const* d_in, const int* in_sizes, int n_in,
                              void* d_out, int out_size, void* d_ws, size_t ws_size,
                              hipStream_t stream) {
  const float* noise = (const float*)d_in[0];  // [64, 14]
  const float* qp    = (const float*)d_in[1];  // [6, 14]
  float* out = (float*)d_out;                  // [64, 14]
  qsim_kernel<<<64, NT, 0, stream>>>(noise, qp, out);
}